// Round 3
// baseline (319.291 us; speedup 1.0000x reference)
//
#include <hip/hip_runtime.h>
#include <hip/hip_bf16.h>

// RGCN layer, input-space aggregation formulation:
//   key = dst*8 + etype; counting-sort edges; per (dst,rel) segment mean of x[src];
//   out = [agg_r0 | ... | agg_r7 | x] (K=1152) @ [W_0;...;W_7;root] + bias, PReLU.
// Single fused MFMA GEMM per 16-dst-row tile; W_r = comp@basis precomputed (bf16).

#define N_NODES 50000
#define N_EDGES 800000
#define N_REL   8
#define CH      128
#define KTOT    1152                       // 8*128 + 128 (root)
#define NSEG    (N_NODES * N_REL)          // 400000
#define DT      16                         // dst rows per fused block
#define SCAN_BLK 1024
#define NSCAN   ((NSEG + SCAN_BLK - 1) / SCAN_BLK)  // 391

typedef __attribute__((ext_vector_type(8))) short bf16x8;
typedef __attribute__((ext_vector_type(4))) float f32x4;

// WcatT[o][k]: B^T view of the [KTOT x CH] weight stack, bf16.
__global__ void k_build_w(const float* __restrict__ basis, const float* __restrict__ comp,
                          const float* __restrict__ root, __hip_bfloat16* __restrict__ WcatT) {
  int idx = blockIdx.x * 256 + threadIdx.x;
  if (idx >= CH * KTOT) return;
  int o = idx / KTOT, k = idx % KTOT;
  float v;
  if (k < N_REL * CH) {
    int r = k >> 7, i = k & (CH - 1);
    float acc = 0.f;
#pragma unroll
    for (int b = 0; b < 8; ++b) acc += comp[r * 8 + b] * basis[(b * CH + i) * CH + o];
    v = acc;
  } else {
    int i = k - N_REL * CH;
    v = root[i * CH + o];
  }
  WcatT[(size_t)o * KTOT + k] = __float2bfloat16(v);
}

__global__ void k_hist(const int* __restrict__ dst, const int* __restrict__ et,
                       int* __restrict__ hist) {
  int e = blockIdx.x * 256 + threadIdx.x;
  if (e < N_EDGES) atomicAdd(&hist[dst[e] * N_REL + et[e]], 1);
}

__global__ void k_scan1(const int* __restrict__ hist, int* __restrict__ off,
                        int* __restrict__ bsum) {
  __shared__ int sd[256];
  int t = threadIdx.x, b = blockIdx.x;
  int base = b * SCAN_BLK + t * 4;
  int v[4]; int s = 0;
#pragma unroll
  for (int j = 0; j < 4; ++j) { int i = base + j; v[j] = (i < NSEG) ? hist[i] : 0; s += v[j]; }
  sd[t] = s; __syncthreads();
  for (int o = 1; o < 256; o <<= 1) {
    int add = (t >= o) ? sd[t - o] : 0; __syncthreads();
    sd[t] += add; __syncthreads();
  }
  int excl = sd[t] - s;
  int run = excl;
#pragma unroll
  for (int j = 0; j < 4; ++j) { int i = base + j; if (i < NSEG) off[i] = run; run += v[j]; }
  if (t == 255) bsum[b] = sd[255];
}

__global__ void k_scan2(int* __restrict__ bsum) {
  __shared__ int sd[512];
  int t = threadIdx.x;
  int v = (t < NSCAN) ? bsum[t] : 0;
  sd[t] = v; __syncthreads();
  for (int o = 1; o < 512; o <<= 1) {
    int add = (t >= o) ? sd[t - o] : 0; __syncthreads();
    sd[t] += add; __syncthreads();
  }
  int excl = (t == 0) ? 0 : sd[t - 1];
  if (t < NSCAN) bsum[t] = excl;
}

__global__ void k_scan3(int* __restrict__ off, const int* __restrict__ bsum) {
  int t = threadIdx.x, b = blockIdx.x;
  int add = bsum[b];
  int base = b * SCAN_BLK + t * 4;
#pragma unroll
  for (int j = 0; j < 4; ++j) { int i = base + j; if (i < NSEG) off[i] += add; }
  if (b == 0 && t == 0) off[NSEG] = N_EDGES;
}

__global__ void k_scatter(const int* __restrict__ src, const int* __restrict__ dst,
                          const int* __restrict__ et, const int* __restrict__ off,
                          int* __restrict__ cursor, int* __restrict__ srcSorted) {
  int e = blockIdx.x * 256 + threadIdx.x;
  if (e >= N_EDGES) return;
  int key = dst[e] * N_REL + et[e];
  int pos = off[key] + atomicAdd(&cursor[key], 1);
  srcSorted[pos] = src[e];
}

__global__ __launch_bounds__(512)
void k_fused(const float* __restrict__ x, const int* __restrict__ off,
             const int* __restrict__ srcSorted, const __hip_bfloat16* __restrict__ WcatT,
             const float* __restrict__ bias, const float* __restrict__ alpha,
             float* __restrict__ out) {
  // row stride 1160 shorts = 2320 B; 2320/16 = 145 ≡ 1 (mod 8) -> uniform LDS bank quads
  __shared__ __hip_bfloat16 A[DT][KTOT + 8];
  int tid = threadIdx.x;
  int wave = tid >> 6, lane = tid & 63;
  int dstBase = blockIdx.x * DT;

  // ---- Phase A: per-(dst,rel) mean aggregation of x[src] rows + root row copy ----
  for (int t = wave; t < DT * N_REL + DT; t += 8) {
    if (t < DT * N_REL) {
      int ld = t >> 3, r = t & 7;
      int seg = (dstBase + ld) * N_REL + r;
      int beg = off[seg], end = off[seg + 1];
      float a0 = 0.f, a1 = 0.f;
      for (int e = beg; e < end; ++e) {
        int s = srcSorted[e];
        const float2 v = *reinterpret_cast<const float2*>(x + (size_t)s * CH + lane * 2);
        a0 += v.x; a1 += v.y;
      }
      float inv = (end > beg) ? 1.0f / (float)(end - beg) : 0.0f;
      A[ld][r * CH + lane * 2]     = __float2bfloat16(a0 * inv);
      A[ld][r * CH + lane * 2 + 1] = __float2bfloat16(a1 * inv);
    } else {
      int ld = t - DT * N_REL;
      const float2 v = *reinterpret_cast<const float2*>(x + (size_t)(dstBase + ld) * CH + lane * 2);
      A[ld][N_REL * CH + lane * 2]     = __float2bfloat16(v.x);
      A[ld][N_REL * CH + lane * 2 + 1] = __float2bfloat16(v.y);
    }
  }
  __syncthreads();

  // ---- Phase B: D[16x16] per wave over K=1152; wave w -> cols [16w, 16w+16) ----
  int r16 = lane & 15, g = lane >> 4;
  f32x4 acc = {0.f, 0.f, 0.f, 0.f};
  const short* Wt = reinterpret_cast<const short*>(WcatT) + (size_t)(wave * 16 + r16) * KTOT;
  const short* Arow = reinterpret_cast<const short*>(&A[r16][0]);
  for (int kk = 0; kk < KTOT / 32; ++kk) {
    int kb = kk * 32 + g * 8;
    bf16x8 af = *reinterpret_cast<const bf16x8*>(Arow + kb);
    bf16x8 bf = *reinterpret_cast<const bf16x8*>(Wt + kb);
    acc = __builtin_amdgcn_mfma_f32_16x16x32_bf16(af, bf, acc, 0, 0, 0);
  }

  int col = wave * 16 + r16;
  float bi = bias[col], al = alpha[col];
#pragma unroll
  for (int rg = 0; rg < 4; ++rg) {
    int row = g * 4 + rg;
    float v = acc[rg] + bi;
    v = (v >= 0.f) ? v : al * v;
    out[(size_t)(dstBase + row) * CH + col] = v;
  }
}

extern "C" void kernel_launch(void* const* d_in, const int* in_sizes, int n_in,
                              void* d_out, int out_size, void* d_ws, size_t ws_size,
                              hipStream_t stream) {
  const float* x     = (const float*)d_in[0];
  const int*   ei    = (const int*)d_in[1];
  const int*   etype = (const int*)d_in[2];
  const float* basis = (const float*)d_in[3];
  const float* comp  = (const float*)d_in[4];
  const float* root  = (const float*)d_in[5];
  const float* bias  = (const float*)d_in[6];
  const float* alpha = (const float*)d_in[7];
  const int* src = ei;
  const int* dst = ei + N_EDGES;
  float* out = (float*)d_out;

  char* ws = (char*)d_ws;
  size_t p = 0;
  auto alloc = [&](size_t bytes) {
    void* q = ws + p;
    p = (p + bytes + 255) & ~(size_t)255;
    return q;
  };
  __hip_bfloat16* WcatT = (__hip_bfloat16*)alloc((size_t)CH * KTOT * sizeof(__hip_bfloat16));
  int* off       = (int*)alloc((size_t)(NSEG + 1) * sizeof(int));
  int* hist      = (int*)alloc((size_t)NSEG * sizeof(int));
  int* cursor    = (int*)alloc((size_t)NSEG * sizeof(int));
  int* bsum      = (int*)alloc((size_t)NSCAN * sizeof(int));
  int* srcSorted = (int*)alloc((size_t)N_EDGES * sizeof(int));

  hipMemsetAsync(hist, 0, (size_t)NSEG * sizeof(int), stream);
  hipMemsetAsync(cursor, 0, (size_t)NSEG * sizeof(int), stream);
  k_build_w<<<(CH * KTOT + 255) / 256, 256, 0, stream>>>(basis, comp, root, WcatT);
  k_hist<<<(N_EDGES + 255) / 256, 256, 0, stream>>>(dst, etype, hist);
  k_scan1<<<NSCAN, 256, 0, stream>>>(hist, off, bsum);
  k_scan2<<<1, 512, 0, stream>>>(bsum);
  k_scan3<<<NSCAN, 256, 0, stream>>>(off, bsum);
  k_scatter<<<(N_EDGES + 255) / 256, 256, 0, stream>>>(src, dst, etype, off, cursor, srcSorted);
  k_fused<<<N_NODES / DT, 512, 0, stream>>>(x, off, srcSorted, WcatT, bias, alpha, out);
}